// Round 10
// baseline (1497.808 us; speedup 1.0000x reference)
//
#include <hip/hip_runtime.h>
#include <hip/hip_bf16.h>
#include <hip/hip_fp16.h>
#include <cstdint>
#include <cstddef>

// B=128 T=96 D=256 H=256 C=8 M=64, COMB=1280
// gates = zc + h @ Uh^T + t @ G^T   (gate interleave n=4j+g)
// x_i eliminated (foldQ static Q, SzM GEMM); out = h @ Wfc^T trailing GEMM.
// R10: fused pipeline, interference-reduced.
//   launches: k_detect -> k_canon(+bar zero) -> k_prep(fold|foldG|foldQ|zzp)
//             -> k_mega(160 blocks):
//     0..127  main  (R5 exchange; W3 stages SzM tile; 1 zcflag poll)
//     128..143 zc-aux : 64-col tiles, zc[t] = Zcat[t] @ Uz^T + bias2
//     144..151 szm-aux: 64-col tiles, SzM[t] = Zl[t] @ Mem2^T + qb
//     152..159 out-aux: 32-col tiles, out[:,t,:] = hSeq[t+1] @ Wfc^T + bfc
// Acyclic flag graph => deadlock-free. All cross-role traffic sc0|sc1 16B.

#define PLANE 24576   // 96*256

using bf16_t = __hip_bfloat16;
typedef __bf16 bf16x8 __attribute__((ext_vector_type(8)));
typedef float  f32x4  __attribute__((ext_vector_type(4)));
typedef unsigned int u32x4 __attribute__((ext_vector_type(4)));

__device__ __forceinline__ float  b2f(bf16_t v){ return __bfloat162float(v); }
__device__ __forceinline__ bf16_t f2b(float v){ return __float2bfloat16(v); }
__device__ __forceinline__ float ldF(const void* p, size_t i, int f32){
  return f32 ? ((const float*)p)[i] : b2f(((const bf16_t*)p)[i]);
}
__device__ __forceinline__ bf16x8 ld_frag(const void* p){
  union { uint4 u; bf16x8 v; } c;
  c.u = *(const uint4*)p;
  return c.v;
}
__device__ __forceinline__ bf16x8 u2b(u32x4 u){
  union { u32x4 u; bf16x8 v; } c; c.u = u; return c.v;
}
__device__ __forceinline__ f32x4 mfma_bf16(bf16x8 a, bf16x8 b, f32x4 c){
  return __builtin_amdgcn_mfma_f32_16x16x32_bf16(a, b, c, 0, 0, 0);
}
__device__ __forceinline__ unsigned pkb(float a, float b){
  union{ bf16_t h; unsigned short u;} ca, cb; ca.h=f2b(a); cb.h=f2b(b);
  return (unsigned)ca.u | ((unsigned)cb.u<<16);
}
__device__ __forceinline__ float h2f_bits(int u){
  union{ unsigned short s; __half h; } c; c.s = (unsigned short)u;
  return __half2float(c.h);
}

// ---- LLC-coherent helpers (sc0 sc1)
__device__ __forceinline__ u32x4 ld_cg(const void* p){
  u32x4 r;
  asm volatile("global_load_dwordx4 %0, %1, off sc0 sc1"
               : "=v"(r) : "v"(p) : "memory");
  return r;
}
__device__ __forceinline__ void st_cg(void* p, u32x4 v){
  asm volatile("global_store_dwordx4 %0, %1, off sc0 sc1"
               :: "v"(p), "v"(v) : "memory");
}
__device__ __forceinline__ int ld_cg_u16(const void* p){
  int r;
  asm volatile("global_load_ushort %0, %1, off sc0 sc1"
               : "=v"(r) : "v"(p) : "memory");
  return r;
}
__device__ __forceinline__ void st_flag(int* p, int v){
  asm volatile("global_store_dword %0, %1, off sc0 sc1"
               :: "v"(p), "v"(v) : "memory");
}
__device__ __forceinline__ int ld_flag(const int* p){
  int r;
  asm volatile("global_load_dword %0, %1, off sc0 sc1\n\ts_waitcnt vmcnt(0)"
               : "=v"(r) : "v"(p) : "memory");
  return r;
}
__device__ __forceinline__ void vm_wait0(){
  asm volatile("s_waitcnt vmcnt(0)" ::: "memory");
  __builtin_amdgcn_sched_barrier(0);
}

// ---------------- dtype detection ----------------
__global__ __launch_bounds__(64) void k_detect(
    const uint32_t* __restrict__ xu, const uint32_t* __restrict__ clu,
    int* __restrict__ flags)
{
  __shared__ int cnt[2];
  int t = threadIdx.x;
  if (t < 2) cnt[t] = 0;
  __syncthreads();
  uint32_t v = xu[2*PLANE + t];
  if (v == 0u || v == 0x3F800000u) atomicAdd(&cnt[0], 1);
  if (clu[2*t + 1] == 0u) atomicAdd(&cnt[1], 1);
  __syncthreads();
  if (t == 0){
    flags[0] = (cnt[0] >= 48) ? 1 : 0;
    flags[1] = (cnt[1] >= 60) ? 1 : 0;
  }
}

// ---------------- canonicalize small tensors (+ zero bar) ----------------
__global__ __launch_bounds__(256) void k_canon(
    const void* __restrict__ Wfc, const void* __restrict__ Xmean,
    const void* __restrict__ bfc, const void* __restrict__ localw,
    const void* __restrict__ globalw, const void* __restrict__ gzw,
    const void* __restrict__ gzb, const void* __restrict__ gzpw,
    const void* __restrict__ gzpb, const int* __restrict__ flags,
    bf16_t* __restrict__ WfcC, bf16_t* __restrict__ XmC,
    bf16_t* __restrict__ bfcC, bf16_t* __restrict__ lwC,
    bf16_t* __restrict__ gwC, float* __restrict__ gzC,
    int* __restrict__ bar)
{
  const int f32 = flags[0];
  int i = blockIdx.x*256 + threadIdx.x;
  if (blockIdx.x < 4) bar[i] = 0;
  if (i < 65536) WfcC[i] = f2b(ldF(Wfc, i, f32));
  if (i < 24576) XmC[i]  = f2b(ldF(Xmean, i, f32));
  if (i < 256)   bfcC[i] = f2b(ldF(bfc, i, f32));
  if (i < 768)   lwC[i]  = f2b(ldF(localw, i, f32));
  if (i < 8)     gwC[i]  = f2b(ldF(globalw, i, f32));
  if (i < 256){
    gzC[i]       = ldF(gzw,  i, f32);
    gzC[256 + i] = ldF(gzb,  i, f32);
    gzC[512 + i] = ldF(gzpw, i, f32);
    gzC[768 + i] = ldF(gzpb, i, f32);
  }
}

// ---------------- fused prep: fold | foldG | foldQ | zzp ----------------
__global__ __launch_bounds__(256) void k_prep(
    const void* __restrict__ Wi, const void* __restrict__ Wf,
    const void* __restrict__ Wo, const void* __restrict__ Wc,
    const void* __restrict__ bi, const void* __restrict__ bfg,
    const void* __restrict__ bo, const void* __restrict__ bcg,
    const void* __restrict__ Wfc, const void* __restrict__ bfc,
    const void* __restrict__ memory, const int* __restrict__ clusters,
    const void* __restrict__ x,
    const bf16_t* __restrict__ XmC, const float* __restrict__ gzC,
    const bf16_t* __restrict__ lwC, const bf16_t* __restrict__ WfcC,
    const bf16_t* __restrict__ bfcC, const int* __restrict__ flags,
    bf16_t* __restrict__ U, bf16_t* __restrict__ Uz,
    float* __restrict__ bias2, bf16_t* __restrict__ G,
    bf16_t* __restrict__ Mem2, bf16_t* __restrict__ Qbf,
    float* __restrict__ qb,
    bf16_t* __restrict__ Zcat, bf16_t* __restrict__ Zl)
{
  __shared__ float sA[4][256];
  __shared__ float red[256];
  const int f32 = flags[0], i64 = flags[1];
  const int bid = blockIdx.x, tid = threadIdx.x;

  if (bid < 1024){
    // ---- fold: U(h-part folded), Uz, bias2
    int n = bid; int g = n & 3; int j = n >> 2;
    const void* Wg = (g==0)?Wi:(g==1)?Wf:(g==2)?Wo:Wc;
    const void* bg = (g==0)?bi:(g==1)?bfg:(g==2)?bo:bcg;
    const size_t wb = (size_t)j*1280;
    int k = tid;
    float acc = 0.f;
    for (int d=0; d<256; ++d)
      acc += ldF(Wg, wb+512+d, f32) * ldF(Wfc, (size_t)d*256+k, f32);
    U[(size_t)n*512 + k]        = f2b(acc + ldF(Wg, wb+1024+k, f32));
    U[(size_t)n*512 + 256 + k]  = f2b(ldF(Wg, wb+768+k, f32));   // unused
    Uz[(size_t)n*512 + k]       = f2b(ldF(Wg, wb+k, f32));
    Uz[(size_t)n*512 + 256 + k] = f2b(ldF(Wg, wb+256+k, f32));
    red[k] = ldF(Wg, wb+512+k, f32) * ldF(bfc, k, f32);
    __syncthreads();
    for (int s=128; s>0; s>>=1){ if (k<s) red[k]+=red[k+s]; __syncthreads(); }
    if (k==0) bias2[n] = red[0] + ldF(bg, j, f32);
  } else if (bid < 1280){
    // ---- foldG: G[n][cm] = sum_d W_gd[n][d] * mem[cm][d]
    int j = bid - 1024;
    const void* Wg[4] = {Wi,Wf,Wo,Wc};
    for (int g=0; g<4; ++g)
      sA[g][tid] = ldF(Wg[g], (size_t)j*1280 + 768 + tid, f32);
    __syncthreads();
    for (int half=0; half<2; ++half){
      int cm = half*256 + tid;
      float a0=0,a1=0,a2=0,a3=0;
      for (int d=0; d<256; ++d){
        float mv = ldF(memory, (size_t)cm*256 + d, f32);
        a0 += sA[0][d]*mv; a1 += sA[1][d]*mv;
        a2 += sA[2][d]*mv; a3 += sA[3][d]*mv;
      }
      G[(size_t)(4*j+0)*512 + cm] = f2b(a0);
      G[(size_t)(4*j+1)*512 + cm] = f2b(a1);
      G[(size_t)(4*j+2)*512 + cm] = f2b(a2);
      G[(size_t)(4*j+3)*512 + cm] = f2b(a3);
    }
  } else if (bid < 1792){
    // ---- foldQ: Q[cm][j], Mem2, qb
    const int cm = bid - 1280; const int c = cm >> 6;
    int cv = i64 ? clusters[2*tid] : clusters[tid];
    float mv = (cv == c+1) ? ldF(memory, (size_t)cm*256 + tid, f32) : 0.f;
    Mem2[(size_t)cm*256 + tid] = f2b(mv);
    float m2 = mv * b2f(lwC[512 + tid]);
    sA[0][tid] = m2;
    red[tid] = m2 * b2f(bfcC[tid]);
    __syncthreads();
    float acc = 0.f;
    for (int d=0; d<256; ++d)
      acc += sA[0][d] * b2f(WfcC[(size_t)d*256 + tid]);
    Qbf[(size_t)cm*256 + tid] = f2b(acc);
    for (int s=128; s>0; s>>=1){ if (tid<s) red[tid]+=red[tid+s]; __syncthreads(); }
    if (tid==0) qb[cm] = red[0];
  } else {
    // ---- zzp: z/zp -> Zcat + Zl
    int r = bid - 1792;            // r = t*128 + b
    int t = r >> 7, b = r & 127, d = tid;
    size_t base = (size_t)b*6*PLANE + (size_t)t*256 + d;
    float xt = ldF(x, base          , f32);
    float xl = ldF(x, base +   PLANE, f32);
    float mk = ldF(x, base + 2*PLANE, f32);
    float de = ldF(x, base + 3*PLANE, f32);
    float xlb= ldF(x, base + 4*PLANE, f32);
    float deb= ldF(x, base + 5*PLANE, f32);
    float mean = b2f(XmC[t*256+d]);
    float dz  = expf(-fmaxf(0.f, de *gzC[d]     + gzC[256+d]));
    float dzp = expf(-fmaxf(0.f, deb*gzC[512+d] + gzC[768+d]));
    float z  = mk*xt + (1.f-mk)*(dz *xl  + (1.f-dz )*mean);
    float zp = mk*xt + (1.f-mk)*(dzp*xlb + (1.f-dzp)*mean);
    Zcat[(size_t)r*512 + d]       = f2b(z);
    Zcat[(size_t)r*512 + 256 + d] = f2b(zp);
    Zl[(size_t)r*256 + d] = f2b(b2f(lwC[d])*z + b2f(lwC[256+d])*zp);
  }
}

// ---------------- k_mega: 160 blocks x 256 threads ----------------
// bar: [g*64+s] barA; [g*64+32+c] barB; [512+a] zcflag(16); [544+a2] szmflag(8)
__global__ __launch_bounds__(256) void k_mega(
    const bf16_t* __restrict__ gwC,
    const bf16_t* __restrict__ U, const bf16_t* __restrict__ G,
    const bf16_t* __restrict__ Qbf, const bf16_t* __restrict__ Uz,
    const float* __restrict__ bias2, const bf16_t* __restrict__ Mem2,
    const float* __restrict__ qb, const bf16_t* __restrict__ Zcat,
    const bf16_t* __restrict__ Zl, const bf16_t* __restrict__ WfcC,
    const bf16_t* __restrict__ bfcC, const int* __restrict__ flags,
    __half* __restrict__ zc, __half* __restrict__ SzM,
    bf16_t* __restrict__ hSeq, bf16_t* __restrict__ tSeq,
    int* __restrict__ bar, void* __restrict__ outv)
{
  __shared__ bf16_t Us[64][260];    // 33,280 B
  __shared__ bf16_t Gs[64][516];    // 66,048 B
  __shared__ bf16_t Qs[64][260];    // 33,280 B (aux: zT/oT scratch)
  __shared__ bf16_t hS[16][260];    //  8,320 B
  __shared__ bf16_t tS[16][516];    // 16,512 B
  __shared__ bf16_t tO[16][64];     //  2,048 B
  __shared__ bf16_t hO[16][16];     //    512 B
  __shared__ __half smS[16][68];    //  2,176 B   total = 162,176 B

  const int bid = blockIdx.x;
  const int tid = threadIdx.x;
  const int W = tid>>6, l = tid&63, q = l>>4, cl = l&15;
  int* zcflag  = bar + 512;
  int* szmflag = bar + 544;

  if (bid < 128){
    // ================= MAIN =================
    const int g = bid & 7, s = bid >> 3;
    const int r0 = g*16;
    const int n0 = s*64;
    int* barA = bar + g*64;
    int* barB = bar + g*64 + 32;

    for (int i=tid; i<64*32; i+=256){ int r=i>>5, c8=(i&31)*8;
      *(uint4*)(&Us[r][c8]) = *(const uint4*)(U + (size_t)(n0+r)*512 + c8); }
    for (int i=tid; i<64*64; i+=256){ int r=i>>6, c8=(i&63)*8;
      *(uint4*)(&Gs[r][c8]) = *(const uint4*)(G + (size_t)(n0+r)*512 + c8); }
    if (s<8)
      for (int i=tid; i<64*32; i+=256){ int r=i>>5, c8=(i&31)*8;
        *(uint4*)(&Qs[r][c8]) = *(const uint4*)(Qbf + (size_t)(s*64+r)*256 + c8); }
    const float gw_c = (s<8)? b2f(gwC[s]) : 0.f;
    const bool sc_wave = (s<8) && (W==0);
    float creg[4] = {0.f,0.f,0.f,0.f};
    __syncthreads();

    for (int t=0; t<96; ++t){
      // ---- Phase A
      if (W==0){
        const int* fp = nullptr; int need = 0; bool act = false;
        if (l < 16){ fp = barA + l; need = t; act = (t>0); }
        else if (l == 16){ fp = zcflag + s; need = t+1; act = true; }
        int f;
        do { f = act ? ld_flag(fp) : 0x7fffffff; } while (__any(f < need));
        if (t>0){
          const bf16_t* hsrc = hSeq + (size_t)t*128*256 + (size_t)r0*256;
          u32x4 hv[8];
#pragma unroll
          for (int k=0;k<8;++k){ int c=l+64*k;
            hv[k] = ld_cg(hsrc + (size_t)(c>>5)*256 + (c&31)*8); }
          vm_wait0();
#pragma unroll
          for (int k=0;k<8;++k){ int c=l+64*k;
            *(u32x4*)(&hS[c>>5][(c&31)*8]) = hv[k]; }
        } else {
#pragma unroll
          for (int k=0;k<8;++k){ int c=l+64*k;
            *(u32x4*)(&hS[c>>5][(c&31)*8]) = (u32x4){0,0,0,0}; }
        }
      } else if (W==3 && s<8){
        // stage SzM tile (16 rows x 64 half) into smS
        if (l==0){ while (ld_flag(szmflag + s) < t+1) {} }
        const __half* ssrc = SzM + ((size_t)t*128 + r0)*512 + s*64;
        u32x4 v0 = ld_cg(ssrc + (size_t)(l>>3)*512 + (l&7)*8);
        u32x4 v1 = ld_cg(ssrc + (size_t)(8+(l>>3))*512 + (l&7)*8);
        vm_wait0();
        *(u32x4*)(&smS[l>>3][(l&7)*8]) = v0;
        *(u32x4*)(&smS[8+(l>>3)][(l&7)*8]) = v1;
      }
      __syncthreads();                // S1: hS + smS ready, zc[t] published
      // zc loads (4 x 2B per lane), consumed after gd-part
      int zr[4];
#pragma unroll
      for (int rr=0; rr<4; ++rr)
        zr[rr] = ld_cg_u16(zc + ((size_t)(t*128)+r0+q*4+rr)*1024 + n0 + W*16 + cl);
      // ---- cluster scores (wave0 of s<8)
      if (sc_wave){
        f32x4 sa[4];
#pragma unroll
        for (int nt=0;nt<4;++nt) sa[nt]=(f32x4){0.f,0.f,0.f,0.f};
#pragma unroll
        for (int ks=0; ks<8; ++ks){
          bf16x8 a = ld_frag(&hS[cl][ks*32 + q*8]);
#pragma unroll
          for (int nt=0; nt<4; ++nt)
            sa[nt] = mfma_bf16(a, ld_frag(&Qs[nt*16+cl][ks*32 + q*8]), sa[nt]);
        }
#pragma unroll
        for (int nt=0; nt<4; ++nt)
#pragma unroll
          for (int rr=0; rr<4; ++rr)
            sa[nt][rr] += __half2float(smS[q*4+rr][nt*16+cl]);
#pragma unroll
        for (int rr=0; rr<4; ++rr){
          float mx = fmaxf(fmaxf(sa[0][rr],sa[1][rr]), fmaxf(sa[2][rr],sa[3][rr]));
          mx = fmaxf(mx, __shfl_xor(mx,1));
          mx = fmaxf(mx, __shfl_xor(mx,2));
          mx = fmaxf(mx, __shfl_xor(mx,4));
          mx = fmaxf(mx, __shfl_xor(mx,8));
          float e0=expf(sa[0][rr]-mx), e1=expf(sa[1][rr]-mx);
          float e2=expf(sa[2][rr]-mx), e3=expf(sa[3][rr]-mx);
          float sm = e0+e1+e2+e3;
          sm += __shfl_xor(sm,1); sm += __shfl_xor(sm,2);
          sm += __shfl_xor(sm,4); sm += __shfl_xor(sm,8);
          float sc = gw_c/sm;
          tO[q*4+rr][ 0+cl] = f2b(e0*sc);
          tO[q*4+rr][16+cl] = f2b(e1*sc);
          tO[q*4+rr][32+cl] = f2b(e2*sc);
          tO[q*4+rr][48+cl] = f2b(e3*sc);
        }
        bf16_t* tdst = tSeq + (size_t)t*128*512 + (size_t)r0*512 + s*64;
#pragma unroll
        for (int k=0;k<2;++k){ int c=l+64*k;
          u32x4 v = *(u32x4*)(&tO[c>>3][(c&7)*8]);
          st_cg(tdst + (size_t)(c>>3)*512 + (c&7)*8, v); }
        vm_wait0();
        if (l==0) st_flag(barB + s, t+1);
      }
      // ---- gate h-part (zc added later)
      f32x4 acc = {0.f,0.f,0.f,0.f};
#pragma unroll
      for (int ks=0; ks<8; ++ks)
        acc = mfma_bf16(ld_frag(&hS[cl][ks*32 + q*8]),
                        ld_frag(&Us[W*16+cl][ks*32 + q*8]), acc);
      // ---- Phase B: wave1 polls 8 flags + stages tS
      if (W==1){
        const int* fp = barB + (l&7);
        int v;
        do { int f = ld_flag(fp); v = (l<8)? f : 0x7fffffff; } while (__any(v < t+1));
        const bf16_t* tsrc = tSeq + (size_t)t*128*512 + (size_t)r0*512;
        u32x4 tv[16];
#pragma unroll
        for (int k=0;k<16;++k){ int c=l+64*k;
          tv[k] = ld_cg(tsrc + (size_t)(c>>6)*512 + (c&63)*8); }
        vm_wait0();
#pragma unroll
        for (int k=0;k<16;++k){ int c=l+64*k;
          *(u32x4*)(&tS[c>>6][(c&63)*8]) = tv[k]; }
      }
      __syncthreads();                // S2: tS ready
      // ---- gate gd-part
#pragma unroll
      for (int ks=0; ks<16; ++ks)
        acc = mfma_bf16(ld_frag(&tS[cl][ks*32 + q*8]),
                        ld_frag(&Gs[W*16+cl][ks*32 + q*8]), acc);
      // ---- add zc
      vm_wait0();
#pragma unroll
      for (int rr=0; rr<4; ++rr) acc[rr] += h2f_bits(zr[rr]);
      // ---- LSTM: each lane one nonlinearity, shuffle transformed values
      const int base = l & ~3;
#pragma unroll
      for (int rr=0; rr<4; ++rr){
        float p = acc[rr];
        float gown = ((l&3)==3) ? tanhf(p) : 1.f/(1.f+expf(-p));
        float iv = __shfl(gown, base+0);
        float fv = __shfl(gown, base+1);
        float ov = __shfl(gown, base+2);
        float cv = __shfl(gown, base+3);
        float cn = fv*creg[rr] + iv*cv;
        creg[rr] = cn;
        float hv = ov * tanhf(cn);
        if ((l&3)==0)
          hO[q*4+rr][W*4 + (cl>>2)] = f2b(hv);
      }
      __syncthreads();                // S3: hO ready
      if (W==0){
        if (l < 32){
          u32x4 v = *(u32x4*)(&hO[l>>1][(l&1)*8]);
          st_cg(hSeq + (size_t)(t+1)*128*256 + (size_t)(r0+(l>>1))*256
                     + s*16 + (l&1)*8, v);
        }
        vm_wait0();
        if (l==0) st_flag(barA + s, t+1);
      }
    }
  } else if (bid < 144){
    // ================= ZC-AUX: 64-col tile =================
    const int a = bid - 128;          // 0..15
    const int n0a = a*64;
    bf16_t (*UzS)[516] = (bf16_t(*)[516])&Gs[0][0];
    __half (*zT)[68]   = (__half(*)[68])&Qs[0][0];   // 128x68 half = 17,408 B
    for (int i=tid; i<64*64; i+=256){ int r=i>>6, c8=(i&63)*8;
      *(uint4*)(&UzS[r][c8]) = *(const uint4*)(Uz + (size_t)(n0a+r)*512 + c8); }
    float bias[4];
#pragma unroll
    for (int ni=0;ni<4;++ni) bias[ni] = bias2[n0a + ni*16 + cl];
    __syncthreads();
    for (int t=0; t<96; ++t){
      f32x4 acc0[4], acc1[4];
#pragma unroll
      for (int ni=0;ni<4;++ni){ acc0[ni]=(f32x4){0,0,0,0}; acc1[ni]=(f32x4){0,0,0,0}; }
      const bf16_t* ar0 = Zcat + ((size_t)t*128 + W*32 + cl)*512;
      const bf16_t* ar1 = ar0 + (size_t)16*512;
#pragma unroll
      for (int ks=0; ks<16; ++ks){
        bf16x8 a0 = ld_frag(ar0 + ks*32 + q*8);
        bf16x8 a1 = ld_frag(ar1 + ks*32 + q*8);
#pragma unroll
        for (int ni=0; ni<4; ++ni){
          bf16x8 b = ld_frag(&UzS[ni*16+cl][ks*32 + q*8]);
          acc0[ni] = mfma_bf16(a0, b, acc0[ni]);
          acc1[ni] = mfma_bf16(a1, b, acc1[ni]);
        }
      }
#pragma unroll
      for (int ni=0; ni<4; ++ni)
#pragma unroll
        for (int rr=0; rr<4; ++rr){
          zT[W*32      + q*4 + rr][ni*16 + cl] = __float2half(acc0[ni][rr] + bias[ni]);
          zT[W*32 + 16 + q*4 + rr][ni*16 + cl] = __float2half(acc1[ni][rr] + bias[ni]);
        }
      __syncthreads();
#pragma unroll
      for (int k=0;k<4;++k){ int c = tid + k*256;   // 1024 chunks of 16B
        int r = c>>3, off = (c&7)*8;
        st_cg(zc + ((size_t)t*128 + r)*1024 + n0a + off, *(u32x4*)(&zT[r][off]));
      }
      vm_wait0();
      __syncthreads();
      if (tid==0) st_flag(zcflag + a, t+1);
    }
  } else if (bid < 152){
    // ================= SZM-AUX: 64-col tile =================
    const int a2 = bid - 144;         // 0..7
    const int cm0 = a2*64;
    bf16_t (*MeS)[260] = (bf16_t(*)[260])&Us[0][0];
    __half (*zT)[68]   = (__half(*)[68])&Qs[0][0];
    for (int i=tid; i<64*32; i+=256){ int r=i>>5, c8=(i&31)*8;
      *(uint4*)(&MeS[r][c8]) = *(const uint4*)(Mem2 + (size_t)(cm0+r)*256 + c8); }
    float bias[4];
#pragma unroll
    for (int ni=0;ni<4;++ni) bias[ni] = qb[cm0 + ni*16 + cl];
    __syncthreads();
    for (int t=0; t<96; ++t){
      f32x4 acc0[4], acc1[4];
#pragma unroll
      for (int ni=0;ni<4;++ni){ acc0[ni]=(f32x4){0,0,0,0}; acc1[ni]=(f32x4){0,0,0,0}; }
      const bf16_t* ar0 = Zl + ((size_t)t*128 + W*32 + cl)*256;
      const bf16_t* ar1 = ar0 + (size_t)16*256;
#pragma unroll
      for (int ks=0; ks<8; ++ks){
        bf16x8 a0 = ld_frag(ar0 + ks*32 + q*8);
        bf16x8 a1 = ld_frag(ar1 + ks*32 + q*8);
#pragma unroll
        for (int ni=0; ni<4; ++ni){
          bf16x8 b = ld_frag(&MeS[ni*16+cl][ks*32 + q*8]);
          acc0[ni] = mfma_bf16(a0, b, acc0[ni]);
          acc1[ni] = mfma_bf16(a1, b, acc1[ni]);
        }
      }
#pragma unroll
      for (int ni=0; ni<4; ++ni)
#pragma unroll
        for (int rr=0; rr<4; ++rr){
          zT[W*32      + q*4 + rr][ni*16 + cl] = __float2half(acc0[ni][rr] + bias[ni]);
          zT[W*32 + 16 + q*4 + rr][ni*16 + cl] = __float2half(acc1[ni][rr] + bias[ni]);
        }
      __syncthreads();
#pragma unroll
      for (int k=0;k<4;++k){ int c = tid + k*256;
        int r = c>>3, off = (c&7)*8;
        st_cg(SzM + ((size_t)t*128 + r)*512 + cm0 + off, *(u32x4*)(&zT[r][off]));
      }
      vm_wait0();
      __syncthreads();
      if (tid==0) st_flag(szmflag + a2, t+1);
    }
  } else {
    // ================= OUT-AUX: 32-col tile =================
    const int a3 = bid - 152;         // 0..7
    const int oc0 = a3*32;
    bf16_t (*WfS)[260] = (bf16_t(*)[260])&Us[0][0];
    float  (*oT)[36]   = (float(*)[36])&Qs[0][0];    // 128x36 f32 = 18,432 B
    for (int i=tid; i<32*32; i+=256){ int r=i>>5, c8=(i&31)*8;
      *(uint4*)(&WfS[r][c8]) = *(const uint4*)(WfcC + (size_t)(oc0+r)*256 + c8); }
    float bias[2];
#pragma unroll
    for (int ni=0;ni<2;++ni) bias[ni] = b2f(bfcC[oc0 + ni*16 + cl]);
    const int f32o = flags[0];
    __syncthreads();
    for (int t=0; t<96; ++t){
      const int* f1 = bar + (l>>4)*64 + (l&15);
      const int* f2 = bar + ((l>>4)+4)*64 + (l&15);
      int fa, fb;
      do { fa = ld_flag(f1); fb = ld_flag(f2); }
      while (__any((fa < t+1) || (fb < t+1)));
      u32x4 av0[8], av1[8];
      const bf16_t* hr0 = hSeq + ((size_t)(t+1)*128 + W*32 + cl)*256;
      const bf16_t* hr1 = hr0 + (size_t)16*256;
#pragma unroll
      for (int ks=0; ks<8; ++ks){
        av0[ks] = ld_cg(hr0 + ks*32 + q*8);
        av1[ks] = ld_cg(hr1 + ks*32 + q*8);
      }
      vm_wait0();
      f32x4 o00={0,0,0,0}, o01={0,0,0,0}, o10={0,0,0,0}, o11={0,0,0,0};
#pragma unroll
      for (int ks=0; ks<8; ++ks){
        bf16x8 b0 = ld_frag(&WfS[cl][ks*32 + q*8]);
        bf16x8 b1 = ld_frag(&WfS[16+cl][ks*32 + q*8]);
        o00 = mfma_bf16(u2b(av0[ks]), b0, o00);
        o01 = mfma_bf16(u2b(av0[ks]), b1, o01);
        o10 = mfma_bf16(u2b(av1[ks]), b0, o10);
        o11 = mfma_bf16(u2b(av1[ks]), b1, o11);
      }
#pragma unroll
      for (int rr=0; rr<4; ++rr){
        oT[W*32      + q*4 + rr][ 0 + cl] = o00[rr] + bias[0];
        oT[W*32      + q*4 + rr][16 + cl] = o01[rr] + bias[1];
        oT[W*32 + 16 + q*4 + rr][ 0 + cl] = o10[rr] + bias[0];
        oT[W*32 + 16 + q*4 + rr][16 + cl] = o11[rr] + bias[1];
      }
      __syncthreads();
      if (f32o){
        float* outF = (float*)outv;
#pragma unroll
        for (int k=0;k<4;++k){ int c = tid + k*256;   // 1024 chunks
          int r = c>>3, off = (c&7)*4;
          u32x4 v = *(u32x4*)(&oT[r][off]);
          st_cg(outF + ((size_t)r*96 + t)*256 + oc0 + off, v);
        }
      } else {
        bf16_t* outB = (bf16_t*)outv;
#pragma unroll
        for (int k=0;k<2;++k){ int c = tid + k*256;   // 512 chunks
          int r = c>>2, off = (c&3)*8;
          u32x4 v;
#pragma unroll
          for (int j=0;j<4;++j) v[j] = pkb(oT[r][off+2*j], oT[r][off+2*j+1]);
          st_cg(outB + ((size_t)r*96 + t)*256 + oc0 + off, v);
        }
      }
      __syncthreads();
    }
  }
}

extern "C" void kernel_launch(void* const* d_in, const int* in_sizes, int n_in,
                              void* d_out, int out_size, void* d_ws, size_t ws_size,
                              hipStream_t stream)
{
  const void* x       = d_in[0];
  const void* Xmean   = d_in[1];
  const int*  clusters= (const int*)d_in[2];
  const void* Wi  = d_in[3];
  const void* bi  = d_in[4];
  const void* Wf  = d_in[5];
  const void* bfp = d_in[6];
  const void* Wo  = d_in[7];
  const void* bo  = d_in[8];
  const void* Wc  = d_in[9];
  const void* bcp = d_in[10];
  const void* Wfc = d_in[11];
  const void* bfc = d_in[12];
  const void* gzw = d_in[13];
  const void* gzb = d_in[14];
  const void* gzpw= d_in[15];
  const void* gzpb= d_in[16];
  const void* memory = d_in[17];
  const void* localw = d_in[18];
  const void* globalw= d_in[19];
  (void)in_sizes; (void)n_in; (void)out_size; (void)ws_size;

  char* ws = (char*)d_ws;
  size_t off = 0;
  auto take = [&](size_t bytes)->char*{
    char* p = ws + off; off = (off + bytes + 255) & ~(size_t)255; return p; };
  int*    flags  = (int*)   take(16);
  int*    bar    = (int*)   take(1024*4);
  bf16_t* U      = (bf16_t*)take((size_t)1024*512*2);     // 1 MB
  bf16_t* Uz     = (bf16_t*)take((size_t)1024*512*2);     // 1 MB
  bf16_t* G      = (bf16_t*)take((size_t)1024*512*2);     // 1 MB
  bf16_t* WfcC   = (bf16_t*)take((size_t)65536*2);
  bf16_t* XmC    = (bf16_t*)take((size_t)24576*2);
  bf16_t* bfcC   = (bf16_t*)take(256*2);
  bf16_t* lwC    = (bf16_t*)take(768*2);
  bf16_t* gwC    = (bf16_t*)take(8*2);
  float*  gzC    = (float*) take(1024*4);
  float*  bias2  = (float*) take(1024*4);
  bf16_t* Mem2   = (bf16_t*)take((size_t)512*256*2);      // 256 KB
  bf16_t* Qbf    = (bf16_t*)take((size_t)512*256*2);      // 256 KB
  float*  qb     = (float*) take(512*4);
  __half* zc     = (__half*)take((size_t)12288*1024*2);   // 25.2 MB
  __half* SzM    = (__half*)take((size_t)12288*512*2);    // 12.6 MB
  bf16_t* Zcat   = (bf16_t*)take((size_t)12288*512*2);    // 12.6 MB
  bf16_t* Zl     = (bf16_t*)take((size_t)12288*256*2);    // 6.3 MB
  bf16_t* tSeq   = (bf16_t*)take((size_t)96*128*512*2);   // 12.6 MB
  bf16_t* hSeq   = (bf16_t*)take((size_t)97*128*256*2);   // 6.4 MB

  k_detect<<<1,    64, 0,stream>>>((const uint32_t*)x, (const uint32_t*)clusters, flags);
  k_canon <<<256,  256,0,stream>>>(Wfc, Xmean, bfc, localw, globalw,
                                   gzw, gzb, gzpw, gzpb, flags,
                                   WfcC, XmC, bfcC, lwC, gwC, gzC, bar);
  k_prep  <<<14080,256,0,stream>>>(Wi,Wf,Wo,Wc, bi,bfp,bo,bcp, Wfc,bfc,
                                   memory, clusters, x,
                                   XmC, gzC, lwC, WfcC, bfcC, flags,
                                   U, Uz, bias2, G, Mem2, Qbf, qb, Zcat, Zl);
  k_mega  <<<160,  256,0,stream>>>(gwC, U, G, Qbf, Uz, bias2, Mem2, qb,
                                   Zcat, Zl, WfcC, bfcC, flags,
                                   zc, SzM, hSeq, tSeq, bar, d_out);
}